// Round 4
// baseline (385.663 us; speedup 1.0000x reference)
//
#include <hip/hip_runtime.h>
#include <hip/hip_bf16.h>

#define NN 50000
#define EE 800000
#define HH 4
#define HDIM 128   // H*D
#define OUT2 256   // fused output cols: fc (128) + res (128)

// ---------------- K0: transpose weights into wT[j][k] (k<128: fc_w, k>=128: res_w)
__global__ void transpose_w_kernel(const float* __restrict__ fc_w,
                                   const float* __restrict__ res_w,
                                   float* __restrict__ wT) {
    int idx = blockIdx.x * 256 + threadIdx.x;      // 128*256 = 32768 elements
    if (idx >= 128 * OUT2) return;
    int k = idx >> 7;          // 0..255 (output col)
    int j = idx & 127;         // input dim
    float v = (k < 128) ? fc_w[k * 128 + j] : res_w[(k - 128) * 128 + j];
    wT[j * OUT2 + k] = v;
}

// ---------------- K1: fused GEMM: h = feat @ fc_w^T (-> ws), res = feat @ res_w^T (-> out)
__global__ __launch_bounds__(256) void gemm_kernel(const float* __restrict__ feat,
                                                   const float* __restrict__ wT,
                                                   float* __restrict__ h,
                                                   float* __restrict__ out,
                                                   int n) {
    __shared__ float fs[32][128];
    int row0 = blockIdx.x * 32;
    int t = threadIdx.x;

    for (int i = t; i < 32 * 32; i += 256) {
        int r = i >> 5;
        int c4 = (i & 31) << 2;
        float4 v;
        if (row0 + r < n) v = *(const float4*)&feat[(size_t)(row0 + r) * 128 + c4];
        else v = make_float4(0.f, 0.f, 0.f, 0.f);
        *(float4*)&fs[r][c4] = v;
    }
    __syncthreads();

    int tc = (t & 63) << 2;
    int tr = t >> 6;
    float acc[8][4];
    #pragma unroll
    for (int rr = 0; rr < 8; ++rr)
        for (int c = 0; c < 4; ++c) acc[rr][c] = 0.f;

    #pragma unroll 4
    for (int j = 0; j < 128; ++j) {
        float4 wv = *(const float4*)&wT[j * OUT2 + tc];
        #pragma unroll
        for (int rr = 0; rr < 8; ++rr) {
            float fv = fs[tr + 4 * rr][j];
            acc[rr][0] = fmaf(fv, wv.x, acc[rr][0]);
            acc[rr][1] = fmaf(fv, wv.y, acc[rr][1]);
            acc[rr][2] = fmaf(fv, wv.z, acc[rr][2]);
            acc[rr][3] = fmaf(fv, wv.w, acc[rr][3]);
        }
    }

    #pragma unroll
    for (int rr = 0; rr < 8; ++rr) {
        int r = row0 + tr + 4 * rr;
        if (r < n) {
            if (tc < 128)
                *(float4*)&h[(size_t)r * 128 + tc] = *(float4*)&acc[rr][0];
            else
                *(float4*)&out[(size_t)r * 128 + (tc - 128)] = *(float4*)&acc[rr][0];
        }
    }
}

// ---------------- K2: el/er = einsum(h, attn_l/r) per node/head
__global__ void elr_kernel(const float* __restrict__ h,
                           const float* __restrict__ al,
                           const float* __restrict__ ar,
                           float* __restrict__ el,
                           float* __restrict__ er,
                           int n) {
    int idx = blockIdx.x * 256 + threadIdx.x;
    int node = idx >> 7;
    if (node >= n) return;
    int hd = idx & 127;
    float v = h[(size_t)node * 128 + hd];
    float a = v * al[hd];
    float b = v * ar[hd];
    #pragma unroll
    for (int off = 16; off > 0; off >>= 1) {
        a += __shfl_down(a, off, 32);
        b += __shfl_down(b, off, 32);
    }
    if ((hd & 31) == 0) {
        el[node * 4 + (hd >> 5)] = a;
        er[node * 4 + (hd >> 5)] = b;
    }
}

// ---------------- K3: degree histogram
__global__ void count_kernel(const int* __restrict__ dst,
                             int* __restrict__ cnt,
                             int e) {
    int ed = blockIdx.x * 256 + threadIdx.x;
    if (ed >= e) return;
    atomicAdd(&cnt[dst[ed]], 1);
}

// ---------------- K4: per-node segment base via wave prefix + one atomic per wave
__global__ void seg_alloc_kernel(const int* __restrict__ cnt,
                                 int* __restrict__ base,
                                 int* __restrict__ cursor,
                                 int* __restrict__ total,
                                 int n) {
    int idx = blockIdx.x * 256 + threadIdx.x;
    int lane = threadIdx.x & 63;
    int c = (idx < n) ? cnt[idx] : 0;
    int pre = c;
    #pragma unroll
    for (int d = 1; d < 64; d <<= 1) {
        int v = __shfl_up(pre, d, 64);
        if (lane >= d) pre += v;
    }
    int wtot = __shfl(pre, 63, 64);
    int wbase = 0;
    if (lane == 63) wbase = atomicAdd(total, wtot);
    wbase = __shfl(wbase, 63, 64);
    if (idx < n) {
        int b = wbase + pre - c;
        base[idx] = b;
        cursor[idx] = b;
    }
}

// ---------------- K5: per-edge score + scatter into per-dst segment + denom atomics
__global__ void edge_scatter_kernel(const int* __restrict__ src,
                                    const int* __restrict__ dst,
                                    const float* __restrict__ el,
                                    const float* __restrict__ er,
                                    int* __restrict__ cursor,
                                    float* __restrict__ coeff_perm,
                                    int* __restrict__ perm_src,
                                    float* __restrict__ denom,
                                    int e) {
    int ed = blockIdx.x * 256 + threadIdx.x;
    if (ed >= e) return;
    int s = src[ed];
    int d = dst[ed];
    float4 a = *(const float4*)&el[(size_t)s * 4];
    float4 b = *(const float4*)&er[(size_t)d * 4];
    float4 c;
    float x;
    x = a.x + b.x; x = (x > 0.f) ? x : 0.2f * x; c.x = __expf(x);
    x = a.y + b.y; x = (x > 0.f) ? x : 0.2f * x; c.y = __expf(x);
    x = a.z + b.z; x = (x > 0.f) ? x : 0.2f * x; c.z = __expf(x);
    x = a.w + b.w; x = (x > 0.f) ? x : 0.2f * x; c.w = __expf(x);
    int pos = atomicAdd(&cursor[d], 1);
    *(float4*)&coeff_perm[(size_t)pos * 4] = c;
    perm_src[pos] = s;
    atomicAdd(&denom[d * 4 + 0], c.x);
    atomicAdd(&denom[d * 4 + 1], c.y);
    atomicAdd(&denom[d * 4 + 2], c.z);
    atomicAdd(&denom[d * 4 + 3], c.w);
}

// ---------------- K6: gather aggregation: 32 threads/node, float4/thread, unroll 4
__global__ __launch_bounds__(256) void gather_agg_kernel(const int* __restrict__ base,
                                                         const int* __restrict__ cnt,
                                                         const int* __restrict__ perm_src,
                                                         const float* __restrict__ coeff_perm,
                                                         const float* __restrict__ denom,
                                                         const float* __restrict__ h,
                                                         float* __restrict__ out) {
    int t = threadIdx.x;
    int node = blockIdx.x * 8 + (t >> 5);   // 8 nodes / block, 50000/8 = 6250 exact
    int ln = t & 31;                        // lane within node
    int d0 = ln << 2;                       // dim base (float4)
    int hh = ln >> 3;                       // head
    int o0 = base[node];
    int deg = cnt[node];
    int o1 = o0 + deg;
    size_t oidx = (size_t)node * 128 + d0;
    float4 acc = *(const float4*)&out[oidx];   // residual already there
    float inv = 1.0f / denom[node * 4 + hh];
    int j = o0;
    for (; j + 3 < o1; j += 4) {
        int s0 = perm_src[j];
        int s1 = perm_src[j + 1];
        int s2 = perm_src[j + 2];
        int s3 = perm_src[j + 3];
        float c0 = coeff_perm[(size_t)j * 4 + hh] * inv;
        float c1 = coeff_perm[(size_t)(j + 1) * 4 + hh] * inv;
        float c2 = coeff_perm[(size_t)(j + 2) * 4 + hh] * inv;
        float c3 = coeff_perm[(size_t)(j + 3) * 4 + hh] * inv;
        float4 h0 = *(const float4*)&h[(size_t)s0 * 128 + d0];
        float4 h1 = *(const float4*)&h[(size_t)s1 * 128 + d0];
        float4 h2 = *(const float4*)&h[(size_t)s2 * 128 + d0];
        float4 h3 = *(const float4*)&h[(size_t)s3 * 128 + d0];
        acc.x = fmaf(c0, h0.x, acc.x); acc.y = fmaf(c0, h0.y, acc.y);
        acc.z = fmaf(c0, h0.z, acc.z); acc.w = fmaf(c0, h0.w, acc.w);
        acc.x = fmaf(c1, h1.x, acc.x); acc.y = fmaf(c1, h1.y, acc.y);
        acc.z = fmaf(c1, h1.z, acc.z); acc.w = fmaf(c1, h1.w, acc.w);
        acc.x = fmaf(c2, h2.x, acc.x); acc.y = fmaf(c2, h2.y, acc.y);
        acc.z = fmaf(c2, h2.z, acc.z); acc.w = fmaf(c2, h2.w, acc.w);
        acc.x = fmaf(c3, h3.x, acc.x); acc.y = fmaf(c3, h3.y, acc.y);
        acc.z = fmaf(c3, h3.z, acc.z); acc.w = fmaf(c3, h3.w, acc.w);
    }
    for (; j < o1; ++j) {
        int s0 = perm_src[j];
        float c0 = coeff_perm[(size_t)j * 4 + hh] * inv;
        float4 h0 = *(const float4*)&h[(size_t)s0 * 128 + d0];
        acc.x = fmaf(c0, h0.x, acc.x); acc.y = fmaf(c0, h0.y, acc.y);
        acc.z = fmaf(c0, h0.z, acc.z); acc.w = fmaf(c0, h0.w, acc.w);
    }
    *(float4*)&out[oidx] = acc;
}

extern "C" void kernel_launch(void* const* d_in, const int* in_sizes, int n_in,
                              void* d_out, int out_size, void* d_ws, size_t ws_size,
                              hipStream_t stream) {
    const float* feat   = (const float*)d_in[0];
    const int*   src    = (const int*)d_in[1];
    const int*   dst    = (const int*)d_in[2];
    const float* fc_w   = (const float*)d_in[3];
    const float* attn_l = (const float*)d_in[4];
    const float* attn_r = (const float*)d_in[5];
    const float* res_w  = (const float*)d_in[6];
    float* out = (float*)d_out;

    // workspace layout
    float* ws = (float*)d_ws;
    float* wT         = ws;                                   // 32768
    float* h          = wT + 128 * OUT2;                      // N*128
    float* el         = h + (size_t)NN * HDIM;                // N*4
    float* er         = el + (size_t)NN * HH;                 // N*4
    float* coeff_perm = er + (size_t)NN * HH;                 // E*4
    // zero-init region: cnt (N ints) + total (1 int) + denom (N*4 floats)
    int*   cnt        = (int*)(coeff_perm + (size_t)EE * HH); // N
    int*   total      = cnt + NN;                             // 1
    float* denom      = (float*)(total + 1);                  // N*4
    int*   base       = (int*)(denom + (size_t)NN * HH);      // N
    int*   cursor     = base + NN;                            // N
    int*   perm_src   = cursor + NN;                          // E

    transpose_w_kernel<<<128, 256, 0, stream>>>(fc_w, res_w, wT);

    int gemm_blocks = (NN + 31) / 32;
    gemm_kernel<<<gemm_blocks, 256, 0, stream>>>(feat, wT, h, out, NN);

    elr_kernel<<<(NN * HDIM) / 256, 256, 0, stream>>>(h, attn_l, attn_r, el, er, NN);

    // one memset covers cnt + total + denom
    hipMemsetAsync(cnt, 0, (size_t)(NN + 1 + NN * HH) * sizeof(int), stream);

    count_kernel<<<(EE + 255) / 256, 256, 0, stream>>>(dst, cnt, EE);

    seg_alloc_kernel<<<(NN + 255) / 256, 256, 0, stream>>>(cnt, base, cursor, total, NN);

    edge_scatter_kernel<<<(EE + 255) / 256, 256, 0, stream>>>(src, dst, el, er, cursor,
                                                              coeff_perm, perm_src, denom, EE);

    gather_agg_kernel<<<NN / 8, 256, 0, stream>>>(base, cnt, perm_src, coeff_perm, denom, h, out);
}

// Round 5
// 231.287 us; speedup vs baseline: 1.6675x; 1.6675x over previous
//
#include <hip/hip_runtime.h>
#include <hip/hip_bf16.h>

#define NN 50000
#define EE 800000
#define HH 4
#define HDIM 128   // H*D
#define OUT2 256   // fused output cols: fc (128) + res (128)

// ---------------- K0: transpose weights into wT[j][k] (k<128: fc_w, k>=128: res_w)
__global__ void transpose_w_kernel(const float* __restrict__ fc_w,
                                   const float* __restrict__ res_w,
                                   float* __restrict__ wT) {
    int idx = blockIdx.x * 256 + threadIdx.x;      // 128*256 = 32768 elements
    if (idx >= 128 * OUT2) return;
    int k = idx >> 7;          // 0..255 (output col)
    int j = idx & 127;         // input dim
    float v = (k < 128) ? fc_w[k * 128 + j] : res_w[(k - 128) * 128 + j];
    wT[j * OUT2 + k] = v;
}

// ---------------- K1: fused GEMM: h = feat @ fc_w^T (-> ws), res = feat @ res_w^T (-> out)
__global__ __launch_bounds__(256) void gemm_kernel(const float* __restrict__ feat,
                                                   const float* __restrict__ wT,
                                                   float* __restrict__ h,
                                                   float* __restrict__ out,
                                                   int n) {
    __shared__ float fs[32][128];
    int row0 = blockIdx.x * 32;
    int t = threadIdx.x;

    for (int i = t; i < 32 * 32; i += 256) {
        int r = i >> 5;
        int c4 = (i & 31) << 2;
        float4 v;
        if (row0 + r < n) v = *(const float4*)&feat[(size_t)(row0 + r) * 128 + c4];
        else v = make_float4(0.f, 0.f, 0.f, 0.f);
        *(float4*)&fs[r][c4] = v;
    }
    __syncthreads();

    int tc = (t & 63) << 2;
    int tr = t >> 6;
    float acc[8][4];
    #pragma unroll
    for (int rr = 0; rr < 8; ++rr)
        for (int c = 0; c < 4; ++c) acc[rr][c] = 0.f;

    #pragma unroll 4
    for (int j = 0; j < 128; ++j) {
        float4 wv = *(const float4*)&wT[j * OUT2 + tc];
        #pragma unroll
        for (int rr = 0; rr < 8; ++rr) {
            float fv = fs[tr + 4 * rr][j];
            acc[rr][0] = fmaf(fv, wv.x, acc[rr][0]);
            acc[rr][1] = fmaf(fv, wv.y, acc[rr][1]);
            acc[rr][2] = fmaf(fv, wv.z, acc[rr][2]);
            acc[rr][3] = fmaf(fv, wv.w, acc[rr][3]);
        }
    }

    #pragma unroll
    for (int rr = 0; rr < 8; ++rr) {
        int r = row0 + tr + 4 * rr;
        if (r < n) {
            if (tc < 128)
                *(float4*)&h[(size_t)r * 128 + tc] = *(float4*)&acc[rr][0];
            else
                *(float4*)&out[(size_t)r * 128 + (tc - 128)] = *(float4*)&acc[rr][0];
        }
    }
}

// ---------------- K2: el/er = einsum(h, attn_l/r) per node/head
__global__ void elr_kernel(const float* __restrict__ h,
                           const float* __restrict__ al,
                           const float* __restrict__ ar,
                           float* __restrict__ el,
                           float* __restrict__ er,
                           int n) {
    int idx = blockIdx.x * 256 + threadIdx.x;
    int node = idx >> 7;
    if (node >= n) return;
    int hd = idx & 127;
    float v = h[(size_t)node * 128 + hd];
    float a = v * al[hd];
    float b = v * ar[hd];
    #pragma unroll
    for (int off = 16; off > 0; off >>= 1) {
        a += __shfl_down(a, off, 32);
        b += __shfl_down(b, off, 32);
    }
    if ((hd & 31) == 0) {
        el[node * 4 + (hd >> 5)] = a;
        er[node * 4 + (hd >> 5)] = b;
    }
}

// ---------------- K3: degree histogram
__global__ void count_kernel(const int* __restrict__ dst,
                             int* __restrict__ cnt,
                             int e) {
    int ed = blockIdx.x * 256 + threadIdx.x;
    if (ed >= e) return;
    atomicAdd(&cnt[dst[ed]], 1);
}

// ---------------- K4: per-node segment base via wave prefix + one atomic per wave
__global__ void seg_alloc_kernel(const int* __restrict__ cnt,
                                 int* __restrict__ base,
                                 int* __restrict__ cursor,
                                 int* __restrict__ total,
                                 int n) {
    int idx = blockIdx.x * 256 + threadIdx.x;
    int lane = threadIdx.x & 63;
    int c = (idx < n) ? cnt[idx] : 0;
    int pre = c;
    #pragma unroll
    for (int d = 1; d < 64; d <<= 1) {
        int v = __shfl_up(pre, d, 64);
        if (lane >= d) pre += v;
    }
    int wtot = __shfl(pre, 63, 64);
    int wbase = 0;
    if (lane == 63) wbase = atomicAdd(total, wtot);
    wbase = __shfl(wbase, 63, 64);
    if (idx < n) {
        int b = wbase + pre - c;
        base[idx] = b;
        cursor[idx] = b;
    }
}

// ---------------- K5: per-edge score + scatter into per-dst segment (no denom atomics)
__global__ void edge_scatter_kernel(const int* __restrict__ src,
                                    const int* __restrict__ dst,
                                    const float* __restrict__ el,
                                    const float* __restrict__ er,
                                    int* __restrict__ cursor,
                                    float* __restrict__ coeff_perm,
                                    int* __restrict__ perm_src,
                                    int e) {
    int ed = blockIdx.x * 256 + threadIdx.x;
    if (ed >= e) return;
    int s = src[ed];
    int d = dst[ed];
    float4 a = *(const float4*)&el[(size_t)s * 4];
    float4 b = *(const float4*)&er[(size_t)d * 4];
    float4 c;
    float x;
    x = a.x + b.x; x = (x > 0.f) ? x : 0.2f * x; c.x = __expf(x);
    x = a.y + b.y; x = (x > 0.f) ? x : 0.2f * x; c.y = __expf(x);
    x = a.z + b.z; x = (x > 0.f) ? x : 0.2f * x; c.z = __expf(x);
    x = a.w + b.w; x = (x > 0.f) ? x : 0.2f * x; c.w = __expf(x);
    int pos = atomicAdd(&cursor[d], 1);
    *(float4*)&coeff_perm[(size_t)pos * 4] = c;
    perm_src[pos] = s;
}

// ---------------- K6: gather aggregation: 32 threads/node; cooperative denom; float4 unroll-4
__global__ __launch_bounds__(256) void gather_agg_kernel(const int* __restrict__ base,
                                                         const int* __restrict__ cnt,
                                                         const int* __restrict__ perm_src,
                                                         const float* __restrict__ coeff_perm,
                                                         const float* __restrict__ h,
                                                         float* __restrict__ out) {
    int t = threadIdx.x;
    int node = blockIdx.x * 8 + (t >> 5);   // 8 nodes / block, 50000/8 = 6250 exact
    int ln = t & 31;                        // lane within node
    int d0 = ln << 2;                       // dim base (float4)
    int hh = ln >> 3;                       // head
    int q  = ln & 7;                        // lane within head group
    int o0 = base[node];
    int deg = cnt[node];
    int o1 = o0 + deg;

    // cooperative denom: 8 lanes per head sum stride-8 (coalesced 128B/step per node group)
    float dsum = 0.f;
    for (int j = o0 + q; j < o1; j += 8)
        dsum += coeff_perm[(size_t)j * 4 + hh];
    dsum += __shfl_xor(dsum, 1, 64);
    dsum += __shfl_xor(dsum, 2, 64);
    dsum += __shfl_xor(dsum, 4, 64);
    float inv = (deg > 0) ? 1.0f / dsum : 0.f;

    size_t oidx = (size_t)node * 128 + d0;
    float4 acc = *(const float4*)&out[oidx];   // residual already there
    int j = o0;
    for (; j + 3 < o1; j += 4) {
        int s0 = perm_src[j];
        int s1 = perm_src[j + 1];
        int s2 = perm_src[j + 2];
        int s3 = perm_src[j + 3];
        float c0 = coeff_perm[(size_t)j * 4 + hh] * inv;
        float c1 = coeff_perm[(size_t)(j + 1) * 4 + hh] * inv;
        float c2 = coeff_perm[(size_t)(j + 2) * 4 + hh] * inv;
        float c3 = coeff_perm[(size_t)(j + 3) * 4 + hh] * inv;
        float4 h0 = *(const float4*)&h[(size_t)s0 * 128 + d0];
        float4 h1 = *(const float4*)&h[(size_t)s1 * 128 + d0];
        float4 h2 = *(const float4*)&h[(size_t)s2 * 128 + d0];
        float4 h3 = *(const float4*)&h[(size_t)s3 * 128 + d0];
        acc.x = fmaf(c0, h0.x, acc.x); acc.y = fmaf(c0, h0.y, acc.y);
        acc.z = fmaf(c0, h0.z, acc.z); acc.w = fmaf(c0, h0.w, acc.w);
        acc.x = fmaf(c1, h1.x, acc.x); acc.y = fmaf(c1, h1.y, acc.y);
        acc.z = fmaf(c1, h1.z, acc.z); acc.w = fmaf(c1, h1.w, acc.w);
        acc.x = fmaf(c2, h2.x, acc.x); acc.y = fmaf(c2, h2.y, acc.y);
        acc.z = fmaf(c2, h2.z, acc.z); acc.w = fmaf(c2, h2.w, acc.w);
        acc.x = fmaf(c3, h3.x, acc.x); acc.y = fmaf(c3, h3.y, acc.y);
        acc.z = fmaf(c3, h3.z, acc.z); acc.w = fmaf(c3, h3.w, acc.w);
    }
    for (; j < o1; ++j) {
        int s0 = perm_src[j];
        float c0 = coeff_perm[(size_t)j * 4 + hh] * inv;
        float4 h0 = *(const float4*)&h[(size_t)s0 * 128 + d0];
        acc.x = fmaf(c0, h0.x, acc.x); acc.y = fmaf(c0, h0.y, acc.y);
        acc.z = fmaf(c0, h0.z, acc.z); acc.w = fmaf(c0, h0.w, acc.w);
    }
    *(float4*)&out[oidx] = acc;
}

extern "C" void kernel_launch(void* const* d_in, const int* in_sizes, int n_in,
                              void* d_out, int out_size, void* d_ws, size_t ws_size,
                              hipStream_t stream) {
    const float* feat   = (const float*)d_in[0];
    const int*   src    = (const int*)d_in[1];
    const int*   dst    = (const int*)d_in[2];
    const float* fc_w   = (const float*)d_in[3];
    const float* attn_l = (const float*)d_in[4];
    const float* attn_r = (const float*)d_in[5];
    const float* res_w  = (const float*)d_in[6];
    float* out = (float*)d_out;

    // workspace layout
    float* ws = (float*)d_ws;
    float* wT         = ws;                                   // 32768
    float* h          = wT + 128 * OUT2;                      // N*128
    float* el         = h + (size_t)NN * HDIM;                // N*4
    float* er         = el + (size_t)NN * HH;                 // N*4
    float* coeff_perm = er + (size_t)NN * HH;                 // E*4
    int*   cnt        = (int*)(coeff_perm + (size_t)EE * HH); // N
    int*   total      = cnt + NN;                             // 1  (adjacent to cnt: one memset)
    int*   base       = total + 1;                            // N
    int*   cursor     = base + NN;                            // N
    int*   perm_src   = cursor + NN;                          // E

    transpose_w_kernel<<<128, 256, 0, stream>>>(fc_w, res_w, wT);

    int gemm_blocks = (NN + 31) / 32;
    gemm_kernel<<<gemm_blocks, 256, 0, stream>>>(feat, wT, h, out, NN);

    elr_kernel<<<(NN * HDIM) / 256, 256, 0, stream>>>(h, attn_l, attn_r, el, er, NN);

    hipMemsetAsync(cnt, 0, (size_t)(NN + 1) * sizeof(int), stream);  // cnt + total

    count_kernel<<<(EE + 255) / 256, 256, 0, stream>>>(dst, cnt, EE);

    seg_alloc_kernel<<<(NN + 255) / 256, 256, 0, stream>>>(cnt, base, cursor, total, NN);

    edge_scatter_kernel<<<(EE + 255) / 256, 256, 0, stream>>>(src, dst, el, er, cursor,
                                                              coeff_perm, perm_src, EE);

    gather_agg_kernel<<<NN / 8, 256, 0, stream>>>(base, cnt, perm_src, coeff_perm, h, out);
}